// Round 1
// baseline (499.305 us; speedup 1.0000x reference)
//
#include <hip/hip_runtime.h>

#define N_NODES 50000
#define N_EDGES 800000
#define FIN 27
#define HF 256
#define NHEAD 4
#define FDIM 64
#define NCAND 8192
#define CTXD 32
#define NBUCK 7
#define NEG 0.2f

// ---------------- CSR build ----------------

__global__ void hist_kernel(const int* __restrict__ dst, int* __restrict__ deg) {
    int e = blockIdx.x * 256 + threadIdx.x;
    if (e < N_EDGES) atomicAdd(&deg[dst[e]], 1);
}

__global__ void scanA_kernel(const int* __restrict__ deg, int* __restrict__ off,
                             int* __restrict__ bsum) {
    __shared__ int s[256];
    int t = threadIdx.x;
    int i = blockIdx.x * 256 + t;
    int v = (i < N_NODES) ? deg[i] : 0;
    s[t] = v;
    __syncthreads();
    for (int d = 1; d < 256; d <<= 1) {
        int add = (t >= d) ? s[t - d] : 0;
        __syncthreads();
        s[t] += add;
        __syncthreads();
    }
    int incl = s[t];
    if (i < N_NODES) off[i] = incl - v;        // block-local exclusive
    if (t == 255) bsum[blockIdx.x] = incl;     // block total
}

__global__ void scanB_kernel(const int* __restrict__ bsum, int* __restrict__ bsumex,
                             int nblocks) {
    __shared__ int s[256];
    int t = threadIdx.x;
    int v = (t < nblocks) ? bsum[t] : 0;
    s[t] = v;
    __syncthreads();
    for (int d = 1; d < 256; d <<= 1) {
        int add = (t >= d) ? s[t - d] : 0;
        __syncthreads();
        s[t] += add;
        __syncthreads();
    }
    bsumex[t] = s[t] - v;  // exclusive
}

__global__ void scanC_kernel(int* __restrict__ off, const int* __restrict__ bsumex,
                             int* __restrict__ cur) {
    int i = blockIdx.x * 256 + threadIdx.x;
    if (i < N_NODES) {
        int v = off[i] + bsumex[i >> 8];
        off[i] = v;
        cur[i] = v;
    }
    if (i == 0) off[N_NODES] = N_EDGES;
}

__global__ void fill_kernel(const int* __restrict__ src, const int* __restrict__ dst,
                            int* __restrict__ cur, int* __restrict__ csr) {
    int e = blockIdx.x * 256 + threadIdx.x;
    if (e < N_EDGES) {
        int d = dst[e];
        int p = atomicAdd(&cur[d], 1);
        csr[p] = src[e];
    }
}

// ---------------- GEMM + attention coefficients ----------------
// thread t (t = head*64 + f) owns output column t; W column cached in registers;
// input row read via wave-uniform (scalar) loads. a_src/a_dst fused via wave reduce.
template <int KD>
__global__ __launch_bounds__(256) void gemm_att_kernel(
    const float* __restrict__ xin, const float* __restrict__ W,
    const float* __restrict__ av, const float* __restrict__ bv,
    float* __restrict__ hout, float* __restrict__ asb, float* __restrict__ adb) {
    int t = threadIdx.x;
    float w[KD];
#pragma unroll
    for (int k = 0; k < KD; k++) w[k] = W[k * HF + t];
    float asv = av[t];
    float adv = bv[t];
    int head = t >> 6;
    for (int n = blockIdx.x; n < N_NODES; n += gridDim.x) {
        const float* xr = xin + (long)n * KD;
        float acc = 0.f;
#pragma unroll
        for (int k = 0; k < KD; k++) acc += xr[k] * w[k];
        hout[(long)n * HF + t] = acc;
        float r1 = acc * asv;
        float r2 = acc * adv;
#pragma unroll
        for (int o = 32; o > 0; o >>= 1) {
            r1 += __shfl_xor(r1, o, 64);
            r2 += __shfl_xor(r2, o, 64);
        }
        if ((t & 63) == 0) {
            asb[n * 4 + head] = r1;
            adb[n * 4 + head] = r2;
        }
    }
}

// ---------------- message passing (one wave per dst node) ----------------
__global__ __launch_bounds__(256) void msg_kernel(
    const float* __restrict__ hsrc,                       // [N,4,64]
    const float* __restrict__ asb, const float* __restrict__ adb,
    const int* __restrict__ off, const int* __restrict__ csr,
    const float* __restrict__ bias, float* __restrict__ outp) {
    int wid = (blockIdx.x * 256 + threadIdx.x) >> 6;
    int lane = threadIdx.x & 63;
    if (wid >= N_NODES) return;
    int dst = wid;

    float ad[4], den[4], acc[4];
#pragma unroll
    for (int h = 0; h < 4; h++) ad[h] = adb[dst * 4 + h];

    // self loop (src = dst)
#pragma unroll
    for (int h = 0; h < 4; h++) {
        float e = asb[dst * 4 + h] + ad[h];
        e = (e >= 0.f) ? e : NEG * e;
        float wgt = expf(e);
        den[h] = wgt;
        acc[h] = wgt * hsrc[(long)dst * HF + h * 64 + lane];
    }

    int beg = off[dst];
    int end = off[dst + 1];
    for (int j = beg; j < end; j++) {
        int s = csr[j];
        const float* ap = asb + s * 4;
        const float* hp = hsrc + (long)s * HF + lane;
#pragma unroll
        for (int h = 0; h < 4; h++) {
            float e = ap[h] + ad[h];
            e = (e >= 0.f) ? e : NEG * e;
            float wgt = expf(e);
            den[h] += wgt;
            acc[h] += wgt * hp[h * 64];
        }
    }
    float v = 0.25f * (acc[0] / den[0] + acc[1] / den[1] + acc[2] / den[2] + acc[3] / den[3])
              + bias[lane];
    outp[(long)dst * FDIM + lane] = (v > 0.f) ? v : (expf(v) - 1.f);
}

// ---------------- tail ----------------

__global__ void pre_kernel(const float* __restrict__ donor, const float* __restrict__ sW1,
                           const float* __restrict__ sb1, const float* __restrict__ lW1,
                           const float* __restrict__ lb1, float* __restrict__ cs,
                           float* __restrict__ cl) {
    int j = threadIdx.x;  // 64
    float a = sb1[j];
    float b = lb1[j];
    for (int m = 0; m < CTXD; m++) {
        float d = donor[m];
        a += d * sW1[(64 + m) * 64 + j];
        b += d * lW1[(64 + m) * 64 + j];
    }
    cs[j] = a;
    cl[j] = b;
}

__global__ __launch_bounds__(256) void start_kernel(
    const float* __restrict__ hout2, const int* __restrict__ cand,
    const float* __restrict__ sW1, const float* __restrict__ cs,
    const float* __restrict__ sW2, const float* __restrict__ sb2,
    float* __restrict__ out) {
    int wid = (blockIdx.x * 256 + threadIdx.x) >> 6;
    int j = threadIdx.x & 63;
    if (wid >= NCAND) return;
    int node = cand[wid];
    const float* hr = hout2 + (long)node * FDIM;
    float hid = cs[j];
#pragma unroll 8
    for (int k = 0; k < 64; k++) hid += hr[k] * sW1[k * 64 + j];
    hid = fmaxf(hid, 0.f) * sW2[j];
#pragma unroll
    for (int o = 32; o > 0; o >>= 1) hid += __shfl_xor(hid, o, 64);
    if (j == 0) out[wid] = hid + sb2[0];
}

__global__ void pool_kernel(const float* __restrict__ hout2, const int* __restrict__ cand,
                            float* __restrict__ pooled) {
    __shared__ float s[256];
    int t = threadIdx.x;
    int lane = t & 63;
    int g = t >> 6;
    float p = 0.f;
    int base = blockIdx.x * 256;  // 32 blocks * 256 cands
    for (int c = base + g; c < base + 256; c += 4) p += hout2[(long)cand[c] * FDIM + lane];
    s[t] = p;
    __syncthreads();
    if (t < 64) atomicAdd(&pooled[t], s[t] + s[t + 64] + s[t + 128] + s[t + 192]);
}

__global__ void length_kernel(const float* __restrict__ pooled, const float* __restrict__ lW1,
                              const float* __restrict__ cl, const float* __restrict__ lW2,
                              const float* __restrict__ lb2, float* __restrict__ out) {
    __shared__ float hid[64];
    int t = threadIdx.x;  // 64
    float a = cl[t];
    for (int k = 0; k < 64; k++) a += (pooled[k] * (1.f / NCAND)) * lW1[k * 64 + t];
    hid[t] = fmaxf(a, 0.f);
    __syncthreads();
    if (t < NBUCK) {
        float acc = lb2[t];
        for (int j = 0; j < 64; j++) acc += hid[j] * lW2[j * NBUCK + t];
        out[NCAND + t] = acc;
    }
}

extern "C" void kernel_launch(void* const* d_in, const int* in_sizes, int n_in,
                              void* d_out, int out_size, void* d_ws, size_t ws_size,
                              hipStream_t stream) {
    const float* x     = (const float*)d_in[0];
    const int*   ei    = (const int*)d_in[1];
    const float* donor = (const float*)d_in[2];
    const int*   cand  = (const int*)d_in[3];
    const float* W1    = (const float*)d_in[4];
    const float* as1   = (const float*)d_in[5];
    const float* ad1   = (const float*)d_in[6];
    const float* b1    = (const float*)d_in[7];
    const float* W2    = (const float*)d_in[8];
    const float* as2   = (const float*)d_in[9];
    const float* ad2   = (const float*)d_in[10];
    const float* b2    = (const float*)d_in[11];
    const float* sW1   = (const float*)d_in[12];
    const float* sb1   = (const float*)d_in[13];
    const float* sW2   = (const float*)d_in[14];
    const float* sb2   = (const float*)d_in[15];
    const float* lW1   = (const float*)d_in[16];
    const float* lb1   = (const float*)d_in[17];
    const float* lW2   = (const float*)d_in[18];
    const float* lb2   = (const float*)d_in[19];
    float* out = (float*)d_out;

    float* wsf    = (float*)d_ws;
    float* h1     = wsf;                 // 50000*256 = 12,800,000 floats
    float* hout1  = h1 + 12800000;       // 3,200,000
    float* hout2  = hout1 + 3200000;     // 3,200,000
    float* asb    = hout2 + 3200000;     // 200,000
    float* adb    = asb + 200000;        // 200,000
    float* cs     = adb + 200000;        // 64
    float* cl     = cs + 64;             // 64
    float* pooled = cl + 64;             // 64
    int* deg    = (int*)(pooled + 64);   // 50000
    int* off    = deg + 50000;           // 50001
    int* cur    = off + 50001;           // 50000
    int* bsum   = cur + 50000;           // 256
    int* bsumex = bsum + 256;            // 256
    int* csr    = bsumex + 256;          // 800000
    // total ~82 MB

    const int* e_src = ei;
    const int* e_dst = ei + N_EDGES;

    hipMemsetAsync(deg, 0, N_NODES * sizeof(int), stream);
    hipMemsetAsync(pooled, 0, 64 * sizeof(float), stream);

    const int NBLK = (N_NODES + 255) / 256;  // 196
    hist_kernel<<<(N_EDGES + 255) / 256, 256, 0, stream>>>(e_dst, deg);
    scanA_kernel<<<NBLK, 256, 0, stream>>>(deg, off, bsum);
    scanB_kernel<<<1, 256, 0, stream>>>(bsum, bsumex, NBLK);
    scanC_kernel<<<NBLK, 256, 0, stream>>>(off, bsumex, cur);
    fill_kernel<<<(N_EDGES + 255) / 256, 256, 0, stream>>>(e_src, e_dst, cur, csr);

    pre_kernel<<<1, 64, 0, stream>>>(donor, sW1, sb1, lW1, lb1, cs, cl);

    gemm_att_kernel<FIN><<<2048, 256, 0, stream>>>(x, W1, as1, ad1, h1, asb, adb);
    msg_kernel<<<(N_NODES + 3) / 4, 256, 0, stream>>>(h1, asb, adb, off, csr, b1, hout1);
    gemm_att_kernel<FDIM><<<2048, 256, 0, stream>>>(hout1, W2, as2, ad2, h1, asb, adb);
    msg_kernel<<<(N_NODES + 3) / 4, 256, 0, stream>>>(h1, asb, adb, off, csr, b2, hout2);

    start_kernel<<<(NCAND + 3) / 4, 256, 0, stream>>>(hout2, cand, sW1, cs, sW2, sb2, out);
    pool_kernel<<<32, 256, 0, stream>>>(hout2, cand, pooled);
    length_kernel<<<1, 64, 0, stream>>>(pooled, lW1, cl, lW2, lb2, out);
}

// Round 2
// 496.893 us; speedup vs baseline: 1.0049x; 1.0049x over previous
//
#include <hip/hip_runtime.h>

#define N_NODES 50000
#define N_EDGES 800000
#define N_TOT   850000   // edges + self loops
#define FIN 27
#define HF 256
#define FDIM 64
#define NCAND 8192
#define CTXD 32
#define NBUCK 7
#define NEG 0.2f

// ---------------- CSR build (self-loops included) ----------------

__global__ void hist_kernel(const int* __restrict__ dst, int* __restrict__ deg) {
    int e = blockIdx.x * 256 + threadIdx.x;
    if (e < N_TOT) {
        int d = (e < N_EDGES) ? dst[e] : (e - N_EDGES);
        atomicAdd(&deg[d], 1);
    }
}

__global__ void scanA_kernel(const int* __restrict__ deg, int* __restrict__ off,
                             int* __restrict__ bsum) {
    __shared__ int s[256];
    int t = threadIdx.x;
    int i = blockIdx.x * 256 + t;
    int v = (i < N_NODES) ? deg[i] : 0;
    s[t] = v;
    __syncthreads();
    for (int d = 1; d < 256; d <<= 1) {
        int add = (t >= d) ? s[t - d] : 0;
        __syncthreads();
        s[t] += add;
        __syncthreads();
    }
    int incl = s[t];
    if (i < N_NODES) off[i] = incl - v;
    if (t == 255) bsum[blockIdx.x] = incl;
}

__global__ void scanB_kernel(const int* __restrict__ bsum, int* __restrict__ bsumex,
                             int nblocks) {
    __shared__ int s[256];
    int t = threadIdx.x;
    int v = (t < nblocks) ? bsum[t] : 0;
    s[t] = v;
    __syncthreads();
    for (int d = 1; d < 256; d <<= 1) {
        int add = (t >= d) ? s[t - d] : 0;
        __syncthreads();
        s[t] += add;
        __syncthreads();
    }
    bsumex[t] = s[t] - v;
}

__global__ void scanC_kernel(int* __restrict__ off, const int* __restrict__ bsumex,
                             int* __restrict__ cur) {
    int i = blockIdx.x * 256 + threadIdx.x;
    if (i < N_NODES) {
        int v = off[i] + bsumex[i >> 8];
        off[i] = v;
        cur[i] = v;
    }
    if (i == 0) off[N_NODES] = N_TOT;
}

__global__ void fill_kernel(const int* __restrict__ src, const int* __restrict__ dst,
                            int* __restrict__ cur, int* __restrict__ csr) {
    int e = blockIdx.x * 256 + threadIdx.x;
    if (e < N_TOT) {
        int d, s;
        if (e < N_EDGES) { d = dst[e]; s = src[e]; }
        else             { d = e - N_EDGES; s = d; }
        int p = atomicAdd(&cur[d], 1);
        csr[p] = s;
    }
}

// ---------------- GEMM + attention dot products ----------------
// thread t = head*64 + f owns output (head,f); stores h transposed to [N, f, head]
// so msg can load all 4 heads of feature f as one float4.
template <int KD>
__global__ __launch_bounds__(256) void gemm_att_kernel(
    const float* __restrict__ xin, const float* __restrict__ W,
    const float* __restrict__ av, const float* __restrict__ bv,
    float* __restrict__ hout, float* __restrict__ asb, float* __restrict__ adb) {
    int t = threadIdx.x;
    float w[KD];
#pragma unroll
    for (int k = 0; k < KD; k++) w[k] = W[k * HF + t];
    float asv = av[t];
    float adv = bv[t];
    int head = t >> 6;
    int f = t & 63;
    for (int n = blockIdx.x; n < N_NODES; n += gridDim.x) {
        const float* xr = xin + (long)n * KD;
        float acc = 0.f;
#pragma unroll
        for (int k = 0; k < KD; k++) acc += xr[k] * w[k];
        hout[(long)n * HF + (f << 2) + head] = acc;   // [N][64][4]
        float r1 = acc * asv;
        float r2 = acc * adv;
#pragma unroll
        for (int o = 32; o > 0; o >>= 1) {
            r1 += __shfl_xor(r1, o, 64);
            r2 += __shfl_xor(r2, o, 64);
        }
        if (f == 0) {
            asb[n * 4 + head] = r1;
            adb[n * 4 + head] = r2;
        }
    }
}

// ---------------- per-edge attention weights (wave per node, lane per edge) ----------------
__global__ __launch_bounds__(256) void att_kernel(
    const float* __restrict__ asb, const float* __restrict__ adb,
    const int* __restrict__ off, const int* __restrict__ csr,
    float* __restrict__ wgt, float* __restrict__ invd) {
    int wid = (blockIdx.x * 256 + threadIdx.x) >> 6;
    int lane = threadIdx.x & 63;
    if (wid >= N_NODES) return;
    const float4 ad4 = *(const float4*)(adb + wid * 4);
    int beg = off[wid], end = off[wid + 1];
    float d0 = 0.f, d1 = 0.f, d2 = 0.f, d3 = 0.f;
    for (int j = beg + lane; j < end; j += 64) {
        int s = csr[j];
        const float4 as4 = *(const float4*)(asb + s * 4);
        float e0 = as4.x + ad4.x; e0 = fmaxf(e0, NEG * e0); float w0 = __expf(e0);
        float e1 = as4.y + ad4.y; e1 = fmaxf(e1, NEG * e1); float w1 = __expf(e1);
        float e2 = as4.z + ad4.z; e2 = fmaxf(e2, NEG * e2); float w2 = __expf(e2);
        float e3 = as4.w + ad4.w; e3 = fmaxf(e3, NEG * e3); float w3 = __expf(e3);
        float4 wv; wv.x = w0; wv.y = w1; wv.z = w2; wv.w = w3;
        *(float4*)(wgt + ((long)j << 2)) = wv;
        d0 += w0; d1 += w1; d2 += w2; d3 += w3;
    }
#pragma unroll
    for (int o = 32; o > 0; o >>= 1) {
        d0 += __shfl_xor(d0, o, 64);
        d1 += __shfl_xor(d1, o, 64);
        d2 += __shfl_xor(d2, o, 64);
        d3 += __shfl_xor(d3, o, 64);
    }
    if (lane == 0) {
        float4 iv;
        iv.x = 0.25f / d0; iv.y = 0.25f / d1; iv.z = 0.25f / d2; iv.w = 0.25f / d3;
        *(float4*)(invd + wid * 4) = iv;
    }
}

// ---------------- message passing (wave per dst; 2 loads + 4 FMA per edge) ----------------
__global__ __launch_bounds__(256) void msg_kernel(
    const float* __restrict__ hsrc,                     // [N][64][4]
    const float* __restrict__ wgt, const int* __restrict__ off,
    const int* __restrict__ csr, const float* __restrict__ invd,
    const float* __restrict__ bias, float* __restrict__ outp) {
    int wid = (blockIdx.x * 256 + threadIdx.x) >> 6;
    int lane = threadIdx.x & 63;
    if (wid >= N_NODES) return;
    float a0 = 0.f, a1 = 0.f, a2 = 0.f, a3 = 0.f;
    int beg = off[wid], end = off[wid + 1];
#pragma unroll 2
    for (int j = beg; j < end; j++) {
        int s = csr[j];
        const float4 h4 = *(const float4*)(hsrc + ((long)s << 8) + (lane << 2));
        const float4 w4 = *(const float4*)(wgt + ((long)j << 2));
        a0 = fmaf(w4.x, h4.x, a0);
        a1 = fmaf(w4.y, h4.y, a1);
        a2 = fmaf(w4.z, h4.z, a2);
        a3 = fmaf(w4.w, h4.w, a3);
    }
    const float4 iv = *(const float4*)(invd + wid * 4);
    float v = a0 * iv.x + a1 * iv.y + a2 * iv.z + a3 * iv.w + bias[lane];
    outp[(long)wid * FDIM + lane] = (v > 0.f) ? v : (__expf(v) - 1.f);
}

// ---------------- tail ----------------

__global__ void pre_kernel(const float* __restrict__ donor, const float* __restrict__ sW1,
                           const float* __restrict__ sb1, const float* __restrict__ lW1,
                           const float* __restrict__ lb1, float* __restrict__ cs,
                           float* __restrict__ cl) {
    int j = threadIdx.x;  // 64
    float a = sb1[j];
    float b = lb1[j];
    for (int m = 0; m < CTXD; m++) {
        float d = donor[m];
        a += d * sW1[(64 + m) * 64 + j];
        b += d * lW1[(64 + m) * 64 + j];
    }
    cs[j] = a;
    cl[j] = b;
}

__global__ __launch_bounds__(256) void start_kernel(
    const float* __restrict__ hout2, const int* __restrict__ cand,
    const float* __restrict__ sW1, const float* __restrict__ cs,
    const float* __restrict__ sW2, const float* __restrict__ sb2,
    float* __restrict__ out) {
    int wid = (blockIdx.x * 256 + threadIdx.x) >> 6;
    int j = threadIdx.x & 63;
    if (wid >= NCAND) return;
    int node = cand[wid];
    const float* hr = hout2 + (long)node * FDIM;
    float hid = cs[j];
#pragma unroll 8
    for (int k = 0; k < 64; k++) hid += hr[k] * sW1[k * 64 + j];
    hid = fmaxf(hid, 0.f) * sW2[j];
#pragma unroll
    for (int o = 32; o > 0; o >>= 1) hid += __shfl_xor(hid, o, 64);
    if (j == 0) out[wid] = hid + sb2[0];
}

__global__ void pool_kernel(const float* __restrict__ hout2, const int* __restrict__ cand,
                            float* __restrict__ pooled) {
    __shared__ float s[256];
    int t = threadIdx.x;
    int lane = t & 63;
    int g = t >> 6;
    float p = 0.f;
    int base = blockIdx.x * 256;
    for (int c = base + g; c < base + 256; c += 4) p += hout2[(long)cand[c] * FDIM + lane];
    s[t] = p;
    __syncthreads();
    if (t < 64) atomicAdd(&pooled[t], s[t] + s[t + 64] + s[t + 128] + s[t + 192]);
}

__global__ void length_kernel(const float* __restrict__ pooled, const float* __restrict__ lW1,
                              const float* __restrict__ cl, const float* __restrict__ lW2,
                              const float* __restrict__ lb2, float* __restrict__ out) {
    __shared__ float hid[64];
    int t = threadIdx.x;  // 64
    float a = cl[t];
    for (int k = 0; k < 64; k++) a += (pooled[k] * (1.f / NCAND)) * lW1[k * 64 + t];
    hid[t] = fmaxf(a, 0.f);
    __syncthreads();
    if (t < NBUCK) {
        float acc = lb2[t];
        for (int j = 0; j < 64; j++) acc += hid[j] * lW2[j * NBUCK + t];
        out[NCAND + t] = acc;
    }
}

extern "C" void kernel_launch(void* const* d_in, const int* in_sizes, int n_in,
                              void* d_out, int out_size, void* d_ws, size_t ws_size,
                              hipStream_t stream) {
    const float* x     = (const float*)d_in[0];
    const int*   ei    = (const int*)d_in[1];
    const float* donor = (const float*)d_in[2];
    const int*   cand  = (const int*)d_in[3];
    const float* W1    = (const float*)d_in[4];
    const float* as1   = (const float*)d_in[5];
    const float* ad1   = (const float*)d_in[6];
    const float* b1    = (const float*)d_in[7];
    const float* W2    = (const float*)d_in[8];
    const float* as2   = (const float*)d_in[9];
    const float* ad2   = (const float*)d_in[10];
    const float* b2    = (const float*)d_in[11];
    const float* sW1   = (const float*)d_in[12];
    const float* sb1   = (const float*)d_in[13];
    const float* sW2   = (const float*)d_in[14];
    const float* sb2   = (const float*)d_in[15];
    const float* lW1   = (const float*)d_in[16];
    const float* lb1   = (const float*)d_in[17];
    const float* lW2   = (const float*)d_in[18];
    const float* lb2   = (const float*)d_in[19];
    float* out = (float*)d_out;

    float* wsf    = (float*)d_ws;
    float* h1     = wsf;                 // 12,800,000 floats ([N][64][4] transposed h)
    float* hmid   = h1 + 12800000;       // 3,200,000 (layer-1 output, reused as layer-2 output)
    float* asb    = hmid + 3200000;      // 200,000
    float* adb    = asb + 200000;        // 200,000
    float* invd   = adb + 200000;        // 200,000
    float* wgt    = invd + 200000;       // 3,400,000 (per-edge weights, CSR order)
    float* cs     = wgt + 3400000;       // 64
    float* cl     = cs + 64;             // 64
    float* pooled = cl + 64;             // 64
    int* deg    = (int*)(pooled + 64);   // 50000
    int* off    = deg + 50000;           // 50001
    int* cur    = off + 50001;           // 50000
    int* bsum   = cur + 50000;           // 256
    int* bsumex = bsum + 256;            // 256
    int* csr    = bsumex + 256;          // 850000
    // total ~84 MB

    const int* e_src = ei;
    const int* e_dst = ei + N_EDGES;

    hipMemsetAsync(deg, 0, N_NODES * sizeof(int), stream);
    hipMemsetAsync(pooled, 0, 64 * sizeof(float), stream);

    const int NBLK = (N_NODES + 255) / 256;  // 196
    const int EBLK = (N_TOT + 255) / 256;
    const int WBLK = (N_NODES + 3) / 4;      // wave-per-node kernels

    hist_kernel<<<EBLK, 256, 0, stream>>>(e_dst, deg);
    scanA_kernel<<<NBLK, 256, 0, stream>>>(deg, off, bsum);
    scanB_kernel<<<1, 256, 0, stream>>>(bsum, bsumex, NBLK);
    scanC_kernel<<<NBLK, 256, 0, stream>>>(off, bsumex, cur);
    fill_kernel<<<EBLK, 256, 0, stream>>>(e_src, e_dst, cur, csr);

    pre_kernel<<<1, 64, 0, stream>>>(donor, sW1, sb1, lW1, lb1, cs, cl);

    gemm_att_kernel<FIN><<<2048, 256, 0, stream>>>(x, W1, as1, ad1, h1, asb, adb);
    att_kernel<<<WBLK, 256, 0, stream>>>(asb, adb, off, csr, wgt, invd);
    msg_kernel<<<WBLK, 256, 0, stream>>>(h1, wgt, off, csr, invd, b1, hmid);

    gemm_att_kernel<FDIM><<<2048, 256, 0, stream>>>(hmid, W2, as2, ad2, h1, asb, adb);
    att_kernel<<<WBLK, 256, 0, stream>>>(asb, adb, off, csr, wgt, invd);
    msg_kernel<<<WBLK, 256, 0, stream>>>(h1, wgt, off, csr, invd, b2, hmid);

    start_kernel<<<(NCAND + 3) / 4, 256, 0, stream>>>(hmid, cand, sW1, cs, sW2, sb2, out);
    pool_kernel<<<32, 256, 0, stream>>>(hmid, cand, pooled);
    length_kernel<<<1, 64, 0, stream>>>(pooled, lW1, cl, lW2, lb2, out);
}

// Round 3
// 383.586 us; speedup vs baseline: 1.3017x; 1.2954x over previous
//
#include <hip/hip_runtime.h>

#define N_NODES 50000
#define N_EDGES 800000
#define N_TOT   850000   // edges + self loops
#define FIN 27
#define HF 256
#define FDIM 64
#define NCAND 8192
#define CTXD 32
#define NBUCK 7
#define NEG 0.2f

typedef unsigned short ushortT;

// ---------------- CSR build (self-loops included) ----------------

__global__ void hist_kernel(const int* __restrict__ dst, int* __restrict__ deg) {
    int e = blockIdx.x * 256 + threadIdx.x;
    if (e < N_TOT) {
        int d = (e < N_EDGES) ? dst[e] : (e - N_EDGES);
        atomicAdd(&deg[d], 1);
    }
}

__global__ void scanA_kernel(const int* __restrict__ deg, int* __restrict__ off,
                             int* __restrict__ bsum) {
    __shared__ int s[256];
    int t = threadIdx.x;
    int i = blockIdx.x * 256 + t;
    int v = (i < N_NODES) ? deg[i] : 0;
    s[t] = v;
    __syncthreads();
    for (int d = 1; d < 256; d <<= 1) {
        int add = (t >= d) ? s[t - d] : 0;
        __syncthreads();
        s[t] += add;
        __syncthreads();
    }
    int incl = s[t];
    if (i < N_NODES) off[i] = incl - v;
    if (t == 255) bsum[blockIdx.x] = incl;
}

__global__ void scanB_kernel(const int* __restrict__ bsum, int* __restrict__ bsumex,
                             int nblocks) {
    __shared__ int s[256];
    int t = threadIdx.x;
    int v = (t < nblocks) ? bsum[t] : 0;
    s[t] = v;
    __syncthreads();
    for (int d = 1; d < 256; d <<= 1) {
        int add = (t >= d) ? s[t - d] : 0;
        __syncthreads();
        s[t] += add;
        __syncthreads();
    }
    bsumex[t] = s[t] - v;
}

__global__ void scanC_kernel(int* __restrict__ off, const int* __restrict__ bsumex,
                             int* __restrict__ cur) {
    int i = blockIdx.x * 256 + threadIdx.x;
    if (i < N_NODES) {
        int v = off[i] + bsumex[i >> 8];
        off[i] = v;
        cur[i] = v;
    }
    if (i == 0) off[N_NODES] = N_TOT;
}

__global__ void fill_kernel(const int* __restrict__ src, const int* __restrict__ dst,
                            int* __restrict__ cur, int* __restrict__ csr) {
    int e = blockIdx.x * 256 + threadIdx.x;
    if (e < N_TOT) {
        int d, s;
        if (e < N_EDGES) { d = dst[e]; s = src[e]; }
        else             { d = e - N_EDGES; s = d; }
        int p = atomicAdd(&cur[d], 1);
        csr[p] = s;
    }
}

// ---------------- GEMM + attention dot products ----------------
// thread t = head*64 + f; stores h as bf16 packed [N][64 feat][4 head]
// so msg can load all 4 heads of feature f as one ushort4 (8B).
template <int KD>
__global__ __launch_bounds__(256) void gemm_att_kernel(
    const float* __restrict__ xin, const float* __restrict__ W,
    const float* __restrict__ av, const float* __restrict__ bv,
    ushortT* __restrict__ hb, float* __restrict__ asb, float* __restrict__ adb) {
    int t = threadIdx.x;
    float w[KD];
#pragma unroll
    for (int k = 0; k < KD; k++) w[k] = W[k * HF + t];
    float asv = av[t];
    float adv = bv[t];
    int head = t >> 6;
    int f = t & 63;
    for (int n = blockIdx.x; n < N_NODES; n += gridDim.x) {
        const float* xr = xin + (long)n * KD;
        float acc = 0.f;
#pragma unroll
        for (int k = 0; k < KD; k++) acc += xr[k] * w[k];
        // round-to-nearest-even f32 -> bf16
        unsigned bits = __float_as_uint(acc);
        unsigned r = (bits + 0x7FFFu + ((bits >> 16) & 1u)) >> 16;
        hb[(long)n * HF + (f << 2) + head] = (ushortT)r;
        float r1 = acc * asv;
        float r2 = acc * adv;
#pragma unroll
        for (int o = 32; o > 0; o >>= 1) {
            r1 += __shfl_xor(r1, o, 64);
            r2 += __shfl_xor(r2, o, 64);
        }
        if (f == 0) {
            asb[n * 4 + head] = r1;
            adb[n * 4 + head] = r2;
        }
    }
}

// ---------------- fused attention + message passing (wave per dst) ----------------
// Phase A (lane-parallel): lane j computes the 4-head weight of edge beg+tile+j.
// Phase B (broadcast via readlane): all 64 lanes gather h[src] (ushort4) and FMA.
__device__ __forceinline__ float bfu(unsigned u) { return __uint_as_float(u << 16); }

__global__ __launch_bounds__(256) void msg_kernel(
    const ushortT* __restrict__ hsrc,                   // [N][64][4] bf16
    const float* __restrict__ asb, const float* __restrict__ adb,
    const int* __restrict__ off, const int* __restrict__ csr,
    const float* __restrict__ bias, float* __restrict__ outp) {
    int wid = (blockIdx.x * 256 + threadIdx.x) >> 6;
    int lane = threadIdx.x & 63;
    if (wid >= N_NODES) return;
    const float4 ad4 = *(const float4*)(adb + wid * 4);
    int beg = off[wid], end = off[wid + 1];
    float a0 = 0.f, a1 = 0.f, a2 = 0.f, a3 = 0.f;
    float d0 = 0.f, d1 = 0.f, d2 = 0.f, d3 = 0.f;
    for (int tb = beg; tb < end; tb += 64) {
        int j = tb + lane;
        float w0 = 0.f, w1 = 0.f, w2 = 0.f, w3 = 0.f;
        int sj = 0;
        if (j < end) {
            sj = csr[j];
            const float4 as4 = *(const float4*)(asb + sj * 4);
            float e0 = as4.x + ad4.x; e0 = fmaxf(e0, NEG * e0); w0 = __expf(e0);
            float e1 = as4.y + ad4.y; e1 = fmaxf(e1, NEG * e1); w1 = __expf(e1);
            float e2 = as4.z + ad4.z; e2 = fmaxf(e2, NEG * e2); w2 = __expf(e2);
            float e3 = as4.w + ad4.w; e3 = fmaxf(e3, NEG * e3); w3 = __expf(e3);
            d0 += w0; d1 += w1; d2 += w2; d3 += w3;
        }
        int cnt = min(end - tb, 64);
#pragma unroll 2
        for (int e = 0; e < cnt; ++e) {
            int   s  = __shfl(sj, e, 64);
            float b0 = __shfl(w0, e, 64);
            float b1 = __shfl(w1, e, 64);
            float b2 = __shfl(w2, e, 64);
            float b3 = __shfl(w3, e, 64);
            ushort4 h4 = *(const ushort4*)(hsrc + ((long)s << 8) + (lane << 2));
            a0 = fmaf(b0, bfu(h4.x), a0);
            a1 = fmaf(b1, bfu(h4.y), a1);
            a2 = fmaf(b2, bfu(h4.z), a2);
            a3 = fmaf(b3, bfu(h4.w), a3);
        }
    }
#pragma unroll
    for (int o = 32; o > 0; o >>= 1) {
        d0 += __shfl_xor(d0, o, 64);
        d1 += __shfl_xor(d1, o, 64);
        d2 += __shfl_xor(d2, o, 64);
        d3 += __shfl_xor(d3, o, 64);
    }
    float v = 0.25f * (a0 / d0 + a1 / d1 + a2 / d2 + a3 / d3) + bias[lane];
    outp[(long)wid * FDIM + lane] = (v > 0.f) ? v : (__expf(v) - 1.f);
}

// ---------------- tail ----------------

__global__ void pre_kernel(const float* __restrict__ donor, const float* __restrict__ sW1,
                           const float* __restrict__ sb1, const float* __restrict__ lW1,
                           const float* __restrict__ lb1, float* __restrict__ cs,
                           float* __restrict__ cl) {
    int j = threadIdx.x;  // 64
    float a = sb1[j];
    float b = lb1[j];
    for (int m = 0; m < CTXD; m++) {
        float d = donor[m];
        a += d * sW1[(64 + m) * 64 + j];
        b += d * lW1[(64 + m) * 64 + j];
    }
    cs[j] = a;
    cl[j] = b;
}

__global__ __launch_bounds__(256) void start_kernel(
    const float* __restrict__ hout2, const int* __restrict__ cand,
    const float* __restrict__ sW1, const float* __restrict__ cs,
    const float* __restrict__ sW2, const float* __restrict__ sb2,
    float* __restrict__ out) {
    int wid = (blockIdx.x * 256 + threadIdx.x) >> 6;
    int j = threadIdx.x & 63;
    if (wid >= NCAND) return;
    int node = cand[wid];
    const float* hr = hout2 + (long)node * FDIM;
    float hid = cs[j];
#pragma unroll 8
    for (int k = 0; k < 64; k++) hid += hr[k] * sW1[k * 64 + j];
    hid = fmaxf(hid, 0.f) * sW2[j];
#pragma unroll
    for (int o = 32; o > 0; o >>= 1) hid += __shfl_xor(hid, o, 64);
    if (j == 0) out[wid] = hid + sb2[0];
}

__global__ void pool_kernel(const float* __restrict__ hout2, const int* __restrict__ cand,
                            float* __restrict__ pooled) {
    __shared__ float s[256];
    int t = threadIdx.x;
    int lane = t & 63;
    int g = t >> 6;
    float p = 0.f;
    int base = blockIdx.x * 256;
    for (int c = base + g; c < base + 256; c += 4) p += hout2[(long)cand[c] * FDIM + lane];
    s[t] = p;
    __syncthreads();
    if (t < 64) atomicAdd(&pooled[t], s[t] + s[t + 64] + s[t + 128] + s[t + 192]);
}

__global__ void length_kernel(const float* __restrict__ pooled, const float* __restrict__ lW1,
                              const float* __restrict__ cl, const float* __restrict__ lW2,
                              const float* __restrict__ lb2, float* __restrict__ out) {
    __shared__ float hid[64];
    int t = threadIdx.x;  // 64
    float a = cl[t];
    for (int k = 0; k < 64; k++) a += (pooled[k] * (1.f / NCAND)) * lW1[k * 64 + t];
    hid[t] = fmaxf(a, 0.f);
    __syncthreads();
    if (t < NBUCK) {
        float acc = lb2[t];
        for (int j = 0; j < 64; j++) acc += hid[j] * lW2[j * NBUCK + t];
        out[NCAND + t] = acc;
    }
}

extern "C" void kernel_launch(void* const* d_in, const int* in_sizes, int n_in,
                              void* d_out, int out_size, void* d_ws, size_t ws_size,
                              hipStream_t stream) {
    const float* x     = (const float*)d_in[0];
    const int*   ei    = (const int*)d_in[1];
    const float* donor = (const float*)d_in[2];
    const int*   cand  = (const int*)d_in[3];
    const float* W1    = (const float*)d_in[4];
    const float* as1   = (const float*)d_in[5];
    const float* ad1   = (const float*)d_in[6];
    const float* b1    = (const float*)d_in[7];
    const float* W2    = (const float*)d_in[8];
    const float* as2   = (const float*)d_in[9];
    const float* ad2   = (const float*)d_in[10];
    const float* b2    = (const float*)d_in[11];
    const float* sW1   = (const float*)d_in[12];
    const float* sb1   = (const float*)d_in[13];
    const float* sW2   = (const float*)d_in[14];
    const float* sb2   = (const float*)d_in[15];
    const float* lW1   = (const float*)d_in[16];
    const float* lb1   = (const float*)d_in[17];
    const float* lW2   = (const float*)d_in[18];
    const float* lb2   = (const float*)d_in[19];
    float* out = (float*)d_out;

    float* wsf    = (float*)d_ws;
    ushortT* h1b  = (ushortT*)wsf;            // 12,800,000 bf16 = 25.6 MB
    float* hmid   = wsf + 6400000;            // 3,200,000 f32 (layer outputs)
    float* asb    = hmid + 3200000;           // 200,000
    float* adb    = asb + 200000;             // 200,000
    float* cs     = adb + 200000;             // 64
    float* cl     = cs + 64;                  // 64
    float* pooled = cl + 64;                  // 64
    int* deg    = (int*)(pooled + 64);        // 50000
    int* off    = deg + 50000;                // 50001
    int* cur    = off + 50001;                // 50000
    int* bsum   = cur + 50000;                // 256
    int* bsumex = bsum + 256;                 // 256
    int* csr    = bsumex + 256;               // 850000
    // total ~45 MB

    const int* e_src = ei;
    const int* e_dst = ei + N_EDGES;

    hipMemsetAsync(deg, 0, N_NODES * sizeof(int), stream);
    hipMemsetAsync(pooled, 0, 64 * sizeof(float), stream);

    const int NBLK = (N_NODES + 255) / 256;  // 196
    const int EBLK = (N_TOT + 255) / 256;
    const int WBLK = (N_NODES + 3) / 4;      // wave-per-node kernels

    hist_kernel<<<EBLK, 256, 0, stream>>>(e_dst, deg);
    scanA_kernel<<<NBLK, 256, 0, stream>>>(deg, off, bsum);
    scanB_kernel<<<1, 256, 0, stream>>>(bsum, bsumex, NBLK);
    scanC_kernel<<<NBLK, 256, 0, stream>>>(off, bsumex, cur);
    fill_kernel<<<EBLK, 256, 0, stream>>>(e_src, e_dst, cur, csr);

    pre_kernel<<<1, 64, 0, stream>>>(donor, sW1, sb1, lW1, lb1, cs, cl);

    gemm_att_kernel<FIN><<<2048, 256, 0, stream>>>(x, W1, as1, ad1, h1b, asb, adb);
    msg_kernel<<<WBLK, 256, 0, stream>>>(h1b, asb, adb, off, csr, b1, hmid);

    gemm_att_kernel<FDIM><<<2048, 256, 0, stream>>>(hmid, W2, as2, ad2, h1b, asb, adb);
    msg_kernel<<<WBLK, 256, 0, stream>>>(h1b, asb, adb, off, csr, b2, hmid);

    start_kernel<<<(NCAND + 3) / 4, 256, 0, stream>>>(hmid, cand, sW1, cs, sW2, sb2, out);
    pool_kernel<<<32, 256, 0, stream>>>(hmid, cand, pooled);
    length_kernel<<<1, 64, 0, stream>>>(pooled, lW1, cl, lW2, lb2, out);
}